// Round 4
// baseline (355.801 us; speedup 1.0000x reference)
//
#include <hip/hip_runtime.h>
#include <stdint.h>

typedef unsigned short u16;
typedef unsigned int u32;
typedef unsigned long long u64;
typedef __attribute__((ext_vector_type(4))) float f32x4;
typedef __attribute__((ext_vector_type(8))) short s16x8;
typedef __attribute__((ext_vector_type(4))) u16 u16x4;
typedef __attribute__((ext_vector_type(2))) u32 u32x2;
typedef __attribute__((ext_vector_type(4))) u32 u32x4;

#define NS 50
#define NH 128
#define NNODE 50000
#define TW 1152      // table row width (Gin|Gout|Ghh)
#define A2P 136      // A2 LDS pitch (elems)

// ---------- helpers ----------
__device__ __forceinline__ u16 f2bf(float f) {
  u32 u = __builtin_bit_cast(u32, f);
  u32 r = (u + 0x7FFFu + ((u >> 16) & 1u)) >> 16;
  return (u16)r;
}
__device__ __forceinline__ float bf2f(u16 u) {
  return __builtin_bit_cast(float, (u32)u << 16);
}
__device__ __forceinline__ float sigm(float x) {
  return 1.0f / (1.0f + __expf(-x));
}
__device__ __forceinline__ float tanh_(float x) {
  return 1.0f - 2.0f / (1.0f + __expf(2.0f * x));
}
__device__ __forceinline__ s16x8 pack8(f32x4 a, f32x4 b) {
  s16x8 r;
  r[0] = (short)f2bf(a[0]); r[1] = (short)f2bf(a[1]);
  r[2] = (short)f2bf(a[2]); r[3] = (short)f2bf(a[3]);
  r[4] = (short)f2bf(b[0]); r[5] = (short)f2bf(b[1]);
  r[6] = (short)f2bf(b[2]); r[7] = (short)f2bf(b[3]);
  return r;
}

// ds_read_b64_tr_b16 pair. col = (addr>>3)&15 selects the column of the
// 128B-aligned 4x16 bf16 tile containing addr; returned elems are rows 0..3
// (stride 32B) of that column; offset:128 -> next tile, same col.
__device__ __forceinline__ s16x8 afrag_tr(const unsigned char* p) {
  u32x2 a, b;
  asm volatile(
      "ds_read_b64_tr_b16 %0, %2\n\t"
      "ds_read_b64_tr_b16 %1, %2 offset:128\n\t"
      "s_waitcnt lgkmcnt(0)"
      : "=&v"(a), "=&v"(b)
      : "v"((const __attribute__((address_space(3))) unsigned char*)p)
      : "memory");
  __builtin_amdgcn_sched_barrier(0);
  u32x4 t;
  t[0] = a[0]; t[1] = a[1]; t[2] = b[0]; t[3] = b[1];
  return __builtin_bit_cast(s16x8, t);
}

// staging index bijection: idx = t_lo + 4*c8 + 32*t_hi  (t = t_lo + 4*t_hi)
// -> within any 16-lane LDS-write phase, all 8 (t%4, c8&1) bank-groups appear
//    exactly 2x => 2-way (free) instead of 8-way conflicts.
__device__ __forceinline__ void stage_decomp(int idx, int& t, int& c8) {
  t = (idx & 3) + ((idx >> 5) << 2);
  c8 = (idx >> 2) & 7;
}

// ---------- kernel 1: fold weights -> UcatT[1152][128] bf16, cvec[3][384] f32 ----------
__global__ __launch_bounds__(256) void k1_prep(
    const float* __restrict__ W_in, const float* __restrict__ b_in,
    const float* __restrict__ W_out, const float* __restrict__ b_out,
    const float* __restrict__ w_ih, const float* __restrict__ b_ih,
    const float* __restrict__ w_hh,
    const float* __restrict__ b_iah, const float* __restrict__ b_oah,
    u16* __restrict__ UcatT, float* __restrict__ cvec)
{
  int e = blockIdx.x * 256 + threadIdx.x;
  if (e < 147456) {
    int j = e >> 7, k = e & 127;
    float s = 0.f;
    if (j < 768) {
      const float* wr = w_ih + (size_t)(j < 384 ? j : j - 384) * 256 + (j < 384 ? 0 : 128);
      const float* Wc = (j < 384 ? W_in : W_out) + k;
      #pragma unroll 8
      for (int h = 0; h < 128; ++h) s += wr[h] * Wc[h * 128];
    } else {
      s = w_hh[(size_t)(j - 768) * 128 + k];
    }
    UcatT[e] = f2bf(s);
  } else if (e < 147456 + 1152) {
    int e2 = e - 147456;
    int which = e2 / 384, g = e2 - which * 384;
    const float* wr = w_ih + (size_t)g * 256;
    float s = 0.f;
    if (which == 0) { for (int h = 0; h < 128; ++h) s += wr[h] * b_in[h]; }
    else if (which == 1) { for (int h = 0; h < 128; ++h) s += wr[128 + h] * b_out[h]; }
    else {
      for (int h = 0; h < 128; ++h) s += wr[h] * b_iah[h] + wr[128 + h] * b_oah[h];
      s += b_ih[g];
    }
    cvec[which * 384 + g] = s;
  }
}

// ---------- kernel 2: node tables T[n][1152] = emb[n] @ UcatT^T (+b_hh on Ghh part) ----------
__global__ __launch_bounds__(256, 2) void k2_tables(
    const float* __restrict__ emb, const u16* __restrict__ UcatT,
    const float* __restrict__ b_hh, u16* __restrict__ T)
{
  int tid = threadIdx.x;
  int w = tid >> 6, l = tid & 63;
  int l16 = l & 15, g4 = l >> 4;
  int n0 = blockIdx.x * 64;

  s16x8 Bf[4][4];
  #pragma unroll
  for (int nt = 0; nt < 4; ++nt) {
    int nb = n0 + nt * 16 + l16; if (nb > NNODE - 1) nb = NNODE - 1;
    const float* ep = emb + (size_t)nb * NH + g4 * 8;
    #pragma unroll
    for (int kt = 0; kt < 4; ++kt) {
      f32x4 x = *(const f32x4*)(ep + kt * 32);
      f32x4 y = *(const f32x4*)(ep + kt * 32 + 4);
      Bf[nt][kt] = pack8(x, y);
    }
  }

  for (int mt = 0; mt < 18; ++mt) {
    int j0 = w * 288 + mt * 16;
    const u16* ap = UcatT + (size_t)(j0 + l16) * 128 + g4 * 8;
    s16x8 Af[4];
    #pragma unroll
    for (int kt = 0; kt < 4; ++kt) Af[kt] = *(const s16x8*)(ap + kt * 32);

    f32x4 acc[4] = {};
    #pragma unroll
    for (int nt = 0; nt < 4; ++nt)
      #pragma unroll
      for (int kt = 0; kt < 4; ++kt)
        acc[nt] = __builtin_amdgcn_mfma_f32_16x16x32_bf16(Af[kt], Bf[nt][kt], acc[nt], 0, 0, 0);

    int jr = j0 + g4 * 4;
    f32x4 bias = {0.f, 0.f, 0.f, 0.f};
    if (jr >= 768) bias = *(const f32x4*)(b_hh + (jr - 768));
    #pragma unroll
    for (int nt = 0; nt < 4; ++nt) {
      int ns = n0 + nt * 16 + l16;
      if (ns < NNODE) {
        u32 lo = (u32)f2bf(acc[nt][0] + bias[0]) | ((u32)f2bf(acc[nt][1] + bias[1]) << 16);
        u32 hi = (u32)f2bf(acc[nt][2] + bias[2]) | ((u32)f2bf(acc[nt][3] + bias[3]) << 16);
        u32x2 v = {lo, hi};
        *(u32x2*)(T + (size_t)ns * TW + jr) = v;
      }
    }
  }
}

// ---------- kernel 3: per-batch fused GEMM + GRU (v2.2: cached loads/stores, 2-way staging) ----------
__global__ __launch_bounds__(256, 4) void k3_main(
    const int* __restrict__ inputs, const float* __restrict__ A,
    const u16* __restrict__ T, const float* __restrict__ cvec,
    const float* __restrict__ emb, float* __restrict__ out)
{
  __shared__ __align__(16) u16 A2lds[64 * A2P];            // 17408 B, [s][t] bf16, zero-padded
  __shared__ __align__(128) unsigned char Glds[4 * 4096];  // 16384 B, [gsub][t(128)][16] bf16
  __shared__ float rsLds[2][64];
  __shared__ u64 rowPtr[100];
  __shared__ int nodeIdx[64];

  const int tid = threadIdx.x;
  const int b = blockIdx.x;
  const int w = tid >> 6, l = tid & 63;
  const int l16 = l & 15, g4 = l >> 4;

  if (tid < 64) nodeIdx[tid] = inputs[b * NS + (tid < NS ? tid : 0)];
  if (tid < 100) {
    int node = inputs[b * NS + (tid < NS ? tid : tid - NS)];
    rowPtr[tid] = (u64)(uintptr_t)T + (u64)node * (TW * 2) + (u64)(tid < NS ? 0 : 768);
  }
  // zero A2 fully + G pad rows (t in [100,128) per gsub) + rs
  for (int i = tid; i < 1088; i += 256) { u32x4 z = {0,0,0,0}; ((u32x4*)A2lds)[i] = z; }
  for (int i = tid; i < 224; i += 256) {
    int gs = i / 56, r = i - gs * 56;
    u32x4 z = {0,0,0,0};
    *(u32x4*)(Glds + gs * 4096 + 3200 + r * 16) = z;
  }
  if (tid < 128) ((float*)rsLds)[tid] = 0.f;
  __syncthreads();

  const float* Ab = A + (size_t)b * (NS * 2 * NS);

  // issue chunk-0 gather early (gate 0, half 0)
  u32x4 st[4];
  #pragma unroll
  for (int i = 0; i < 4; ++i) {
    int idx = tid + i * 256;
    if (idx < 800) {
      int t, c8; stage_decomp(idx, t, c8);
      st[i] = *(const u32x4*)(uintptr_t)(rowPtr[t] + (u64)(c8 * 16));
    }
  }

  // stage A2 (f32 -> bf16), cached loads (rowsum pass below re-hits L2)
  #pragma unroll
  for (int i = 0; i < 5; ++i) {
    int idx = tid + i * 256;
    if (idx < 1250) {
      int s = idx / 25, q = idx - s * 25;
      f32x4 v = *(const f32x4*)(Ab + s * 100 + q * 4);
      u32 lo = (u32)f2bf(v[0]) | ((u32)f2bf(v[1]) << 16);
      u32 hi = (u32)f2bf(v[2]) | ((u32)f2bf(v[3]) << 16);
      u32x2 pv = {lo, hi};
      *(u32x2*)(A2lds + s * A2P + q * 4) = pv;
    }
  }

  // f32 rowsums (for epilogue bias) — L2 hits
  if (tid < 100) {
    int s = tid < NS ? tid : tid - NS;
    const float* ap = Ab + s * 100 + (tid < NS ? 0 : NS);
    float sum = 0.f;
    #pragma unroll 10
    for (int t = 0; t < NS; ++t) sum += ap[t];
    rsLds[tid < NS ? 0 : 1][s] = sum;
  }

  // write chunk 0
  #pragma unroll
  for (int i = 0; i < 4; ++i) {
    int idx = tid + i * 256;
    if (idx < 800) {
      int t, c8; stage_decomp(idx, t, c8);
      *(u32x4*)(Glds + (c8 >> 1) * 4096 + t * 32 + (c8 & 1) * 16) = st[i];
    }
  }
  __syncthreads();

  f32x4 accs[3][4] = {};
  // tr-read base: wave's gsub + tile-row group (g4*256) + column encoded as l16*8
  const unsigned char* trBase = Glds + w * 4096 + g4 * 256 + l16 * 8;

  #pragma unroll
  for (int c = 0; c < 6; ++c) {
    const int nc = c + 1;
    // T14: issue next chunk's gather before this chunk's MFMA
    if (nc < 6) {
      const u64 off = (u64)((nc % 3) * 256 + (nc / 3) * 128);
      #pragma unroll
      for (int i = 0; i < 4; ++i) {
        int idx = tid + i * 256;
        if (idx < 800) {
          int t, c8; stage_decomp(idx, t, c8);
          st[i] = *(const u32x4*)(uintptr_t)(rowPtr[t] + off + (u64)(c8 * 16));
        }
      }
    }
    // MFMA chunk c (gate = c%3)
    {
      const int gate = c % 3;
      #pragma unroll
      for (int kt = 0; kt < 4; ++kt) {
        s16x8 Bf[4];
        #pragma unroll
        for (int nt = 0; nt < 4; ++nt)
          Bf[nt] = *(const s16x8*)(A2lds + (nt * 16 + l16) * A2P + kt * 32 + g4 * 8);
        s16x8 Af = afrag_tr(trBase + kt * 1024);
        #pragma unroll
        for (int nt = 0; nt < 4; ++nt)
          accs[gate][nt] = __builtin_amdgcn_mfma_f32_16x16x32_bf16(Af, Bf[nt], accs[gate][nt], 0, 0, 0);
      }
    }
    __syncthreads();
    if (nc < 6) {
      #pragma unroll
      for (int i = 0; i < 4; ++i) {
        int idx = tid + i * 256;
        if (idx < 800) {
          int t, c8; stage_decomp(idx, t, c8);
          *(u32x4*)(Glds + (c8 >> 1) * 4096 + t * 32 + (c8 & 1) * 16) = st[i];
        }
      }
    }
    // epilogue per h-half (chunks r,i,n complete)
    if (c == 2 || c == 5) {
      const int half = c / 3;
      const int h0 = half * 64 + w * 16 + g4 * 4;
      f32x4 cin[3], cou[3], cz[3];
      #pragma unroll
      for (int gate = 0; gate < 3; ++gate) {
        int g = gate * 128 + h0;
        cin[gate] = *(const f32x4*)(cvec + g);
        cou[gate] = *(const f32x4*)(cvec + 384 + g);
        cz[gate]  = *(const f32x4*)(cvec + 768 + g);
      }
      #pragma unroll
      for (int nt = 0; nt < 4; ++nt) {
        int s = nt * 16 + l16;
        int node = nodeIdx[s];
        float rin = rsLds[0][s], rou = rsLds[1][s];
        const u16* Trow = T + (size_t)node * TW + 768 + h0;
        u16x4 gr = *(const u16x4*)(Trow);
        u16x4 gi = *(const u16x4*)(Trow + 128);
        u16x4 gn = *(const u16x4*)(Trow + 256);
        f32x4 hid = *(const f32x4*)(emb + (size_t)node * NH + h0);
        f32x4 res;
        #pragma unroll
        for (int r = 0; r < 4; ++r) {
          float vr = accs[0][nt][r] + rin * cin[0][r] + rou * cou[0][r] + cz[0][r] + bf2f(gr[r]);
          float vi = accs[1][nt][r] + rin * cin[1][r] + rou * cou[1][r] + cz[1][r] + bf2f(gi[r]);
          float vn = accs[2][nt][r] + rin * cin[2][r] + rou * cou[2][r] + cz[2][r];
          float rr = sigm(vr);
          float ii = sigm(vi);
          float nn = tanh_(vn + rr * bf2f(gn[r]));
          res[r] = nn + ii * (hid[r] - nn);
        }
        if (s < NS)
          *(f32x4*)(out + ((size_t)b * NS + s) * NH + h0) = res;
      }
      #pragma unroll
      for (int g2 = 0; g2 < 3; ++g2)
        #pragma unroll
        for (int nt = 0; nt < 4; ++nt) {
          f32x4 z = {0.f, 0.f, 0.f, 0.f};
          accs[g2][nt] = z;
        }
    }
    __syncthreads();
  }
}

// ---------- launcher ----------
extern "C" void kernel_launch(void* const* d_in, const int* in_sizes, int n_in,
                              void* d_out, int out_size, void* d_ws, size_t ws_size,
                              hipStream_t stream) {
  const int*   inputs = (const int*)  d_in[0];
  const float* A      = (const float*)d_in[1];
  const float* emb    = (const float*)d_in[2];
  const float* W_in   = (const float*)d_in[3];
  const float* b_in   = (const float*)d_in[4];
  const float* W_out  = (const float*)d_in[5];
  const float* b_out  = (const float*)d_in[6];
  const float* w_ih   = (const float*)d_in[7];
  const float* b_ih   = (const float*)d_in[8];
  const float* w_hh   = (const float*)d_in[9];
  const float* b_hh   = (const float*)d_in[10];
  const float* b_iah  = (const float*)d_in[11];
  const float* b_oah  = (const float*)d_in[12];

  // ws layout: T (50000*1152 bf16 = 115,200,000 B) | UcatT (294,912 B) | cvec (4,608 B)
  u16*   T     = (u16*)d_ws;
  u16*   UcatT = (u16*)((char*)d_ws + 115200000);
  float* cvec  = (float*)((char*)d_ws + 115200000 + 294912);

  k1_prep<<<dim3(581), dim3(256), 0, stream>>>(W_in, b_in, W_out, b_out, w_ih, b_ih,
                                               w_hh, b_iah, b_oah, UcatT, cvec);
  k2_tables<<<dim3(782), dim3(256), 0, stream>>>(emb, UcatT, b_hh, T);
  k3_main<<<dim3(4096), dim3(256), 0, stream>>>(inputs, A, T, cvec, emb, (float*)d_out);
}

// Round 5
// 292.067 us; speedup vs baseline: 1.2182x; 1.2182x over previous
//
#include <hip/hip_runtime.h>
#include <stdint.h>

typedef unsigned short u16;
typedef unsigned int u32;
typedef unsigned long long u64;
typedef __attribute__((ext_vector_type(4))) float f32x4;
typedef __attribute__((ext_vector_type(8))) short s16x8;
typedef __attribute__((ext_vector_type(4))) u16 u16x4;
typedef __attribute__((ext_vector_type(2))) u32 u32x2;
typedef __attribute__((ext_vector_type(4))) u32 u32x4;

#define NS 50
#define NH 128
#define NNODE 50000
#define TW 1152      // table row width in u16 (Gin|Gout|Ghh)
#define GSUB 3328    // bytes per staged g-subtile: 26 tiles x 128B (rows 100..103 zero)

// ---------- helpers ----------
__device__ __forceinline__ u16 f2bf(float f) {
  u32 u = __builtin_bit_cast(u32, f);
  u32 r = (u + 0x7FFFu + ((u >> 16) & 1u)) >> 16;
  return (u16)r;
}
__device__ __forceinline__ float bf2f(u16 u) {
  return __builtin_bit_cast(float, (u32)u << 16);
}
__device__ __forceinline__ float sigm(float x) {
  return 1.0f / (1.0f + __expf(-x));
}
__device__ __forceinline__ float tanh_(float x) {
  return 1.0f - 2.0f / (1.0f + __expf(2.0f * x));
}
__device__ __forceinline__ s16x8 pack8(f32x4 a, f32x4 b) {
  s16x8 r;
  r[0] = (short)f2bf(a[0]); r[1] = (short)f2bf(a[1]);
  r[2] = (short)f2bf(a[2]); r[3] = (short)f2bf(a[3]);
  r[4] = (short)f2bf(b[0]); r[5] = (short)f2bf(b[1]);
  r[6] = (short)f2bf(b[2]); r[7] = (short)f2bf(b[3]);
  return r;
}
// truncating f32->bf16 pack via v_perm (1 op / 2 elems); A in [0,1): err <= 2^-9
__device__ __forceinline__ s16x8 pack8_trunc(f32x4 a, f32x4 b) {
  u32x4 ua = __builtin_bit_cast(u32x4, a);
  u32x4 ub = __builtin_bit_cast(u32x4, b);
  u32x4 t;
  t[0] = __builtin_amdgcn_perm(ua[1], ua[0], 0x07060302u);
  t[1] = __builtin_amdgcn_perm(ua[3], ua[2], 0x07060302u);
  t[2] = __builtin_amdgcn_perm(ub[1], ub[0], 0x07060302u);
  t[3] = __builtin_amdgcn_perm(ub[3], ub[2], 0x07060302u);
  return __builtin_bit_cast(s16x8, t);
}

// batched tr-reads: all 4 kt fragments of one gate, ONE lgkmcnt(0).
// tiles: kt*8 + g4*2 for kt<3 (p0 = gb + g4*256), fixed tile 24/25 for kt=3 (p3 = gb + 3072).
__device__ __forceinline__ void afrag_tr8(const unsigned char* p0,
                                          const unsigned char* p3,
                                          s16x8 Af[4]) {
  u32x2 r0, r1, r2, r3, r4, r5, r6, r7;
  asm volatile(
      "ds_read_b64_tr_b16 %0, %8\n\t"
      "ds_read_b64_tr_b16 %1, %8 offset:128\n\t"
      "ds_read_b64_tr_b16 %2, %8 offset:1024\n\t"
      "ds_read_b64_tr_b16 %3, %8 offset:1152\n\t"
      "ds_read_b64_tr_b16 %4, %8 offset:2048\n\t"
      "ds_read_b64_tr_b16 %5, %8 offset:2176\n\t"
      "ds_read_b64_tr_b16 %6, %9\n\t"
      "ds_read_b64_tr_b16 %7, %9 offset:128\n\t"
      "s_waitcnt lgkmcnt(0)"
      : "=&v"(r0), "=&v"(r1), "=&v"(r2), "=&v"(r3),
        "=&v"(r4), "=&v"(r5), "=&v"(r6), "=&v"(r7)
      : "v"((const __attribute__((address_space(3))) unsigned char*)p0),
        "v"((const __attribute__((address_space(3))) unsigned char*)p3)
      : "memory");
  __builtin_amdgcn_sched_barrier(0);
  u32x4 t0; t0[0] = r0[0]; t0[1] = r0[1]; t0[2] = r1[0]; t0[3] = r1[1];
  u32x4 t1; t1[0] = r2[0]; t1[1] = r2[1]; t1[2] = r3[0]; t1[3] = r3[1];
  u32x4 t2; t2[0] = r4[0]; t2[1] = r4[1]; t2[2] = r5[0]; t2[3] = r5[1];
  u32x4 t3; t3[0] = r6[0]; t3[1] = r6[1]; t3[2] = r7[0]; t3[3] = r7[1];
  Af[0] = __builtin_bit_cast(s16x8, t0);
  Af[1] = __builtin_bit_cast(s16x8, t1);
  Af[2] = __builtin_bit_cast(s16x8, t2);
  Af[3] = __builtin_bit_cast(s16x8, t3);
}

// staging bijection: idx in [0,4800) -> (t in [0,100), c in [0,48))
// t = ((idx>>1)&3)*25 + (idx>>3)%25 ; c = ((idx>>3)/25)*2 + (idx&1)
// 8 consecutive lanes cover all 8 (t%4, c%2) bank-octets -> conflict-free b128 writes.
__device__ __forceinline__ void stage_decomp(int idx, int& t, int& c) {
  int e3 = idx >> 3;
  int t_hi = e3 % 25;
  int c_hi = e3 / 25;
  t = ((idx >> 1) & 3) * 25 + t_hi;
  c = c_hi * 2 + (idx & 1);
}
// staged column group gs (0..23) -> byte offset of its 16 g-cols inside Gin/Gout row
// gs = w*6 + gate*2 + p  ->  g_base = gate*128 + w*32 + p*16
__device__ __forceinline__ int gs_to_gbyte(int gs) {
  int wv = gs / 6, ml = gs - wv * 6;
  return ((ml >> 1) * 128 + wv * 32 + (ml & 1) * 16) * 2;
}

// ---------- kernel 1: fold weights -> UcatT[1152][128] bf16, cvec[3][384] f32 ----------
__global__ __launch_bounds__(256) void k1_prep(
    const float* __restrict__ W_in, const float* __restrict__ b_in,
    const float* __restrict__ W_out, const float* __restrict__ b_out,
    const float* __restrict__ w_ih, const float* __restrict__ b_ih,
    const float* __restrict__ w_hh,
    const float* __restrict__ b_iah, const float* __restrict__ b_oah,
    u16* __restrict__ UcatT, float* __restrict__ cvec)
{
  int e = blockIdx.x * 256 + threadIdx.x;
  if (e < 147456) {
    int j = e >> 7, k = e & 127;
    float s = 0.f;
    if (j < 768) {
      const float* wr = w_ih + (size_t)(j < 384 ? j : j - 384) * 256 + (j < 384 ? 0 : 128);
      const float* Wc = (j < 384 ? W_in : W_out) + k;
      #pragma unroll 8
      for (int h = 0; h < 128; ++h) s += wr[h] * Wc[h * 128];
    } else {
      s = w_hh[(size_t)(j - 768) * 128 + k];
    }
    UcatT[e] = f2bf(s);
  } else if (e < 147456 + 1152) {
    int e2 = e - 147456;
    int which = e2 / 384, g = e2 - which * 384;
    const float* wr = w_ih + (size_t)g * 256;
    float s = 0.f;
    if (which == 0) { for (int h = 0; h < 128; ++h) s += wr[h] * b_in[h]; }
    else if (which == 1) { for (int h = 0; h < 128; ++h) s += wr[128 + h] * b_out[h]; }
    else {
      for (int h = 0; h < 128; ++h) s += wr[h] * b_iah[h] + wr[128 + h] * b_oah[h];
      s += b_ih[g];
    }
    cvec[which * 384 + g] = s;
  }
}

// ---------- kernel 2: node tables T[n][1152] = emb[n] @ UcatT^T (+b_hh on Ghh part) ----------
__global__ __launch_bounds__(256, 2) void k2_tables(
    const float* __restrict__ emb, const u16* __restrict__ UcatT,
    const float* __restrict__ b_hh, u16* __restrict__ T)
{
  int tid = threadIdx.x;
  int w = tid >> 6, l = tid & 63;
  int l16 = l & 15, g4 = l >> 4;
  int n0 = blockIdx.x * 64;

  s16x8 Bf[4][4];
  #pragma unroll
  for (int nt = 0; nt < 4; ++nt) {
    int nb = n0 + nt * 16 + l16; if (nb > NNODE - 1) nb = NNODE - 1;
    const float* ep = emb + (size_t)nb * NH + g4 * 8;
    #pragma unroll
    for (int kt = 0; kt < 4; ++kt) {
      f32x4 x = *(const f32x4*)(ep + kt * 32);
      f32x4 y = *(const f32x4*)(ep + kt * 32 + 4);
      Bf[nt][kt] = pack8(x, y);
    }
  }

  for (int mt = 0; mt < 18; ++mt) {
    int j0 = w * 288 + mt * 16;
    const u16* ap = UcatT + (size_t)(j0 + l16) * 128 + g4 * 8;
    s16x8 Af[4];
    #pragma unroll
    for (int kt = 0; kt < 4; ++kt) Af[kt] = *(const s16x8*)(ap + kt * 32);

    f32x4 acc[4] = {};
    #pragma unroll
    for (int nt = 0; nt < 4; ++nt)
      #pragma unroll
      for (int kt = 0; kt < 4; ++kt)
        acc[nt] = __builtin_amdgcn_mfma_f32_16x16x32_bf16(Af[kt], Bf[nt][kt], acc[nt], 0, 0, 0);

    int jr = j0 + g4 * 4;
    f32x4 bias = {0.f, 0.f, 0.f, 0.f};
    if (jr >= 768) bias = *(const f32x4*)(b_hh + (jr - 768));
    #pragma unroll
    for (int nt = 0; nt < 4; ++nt) {
      int ns = n0 + nt * 16 + l16;
      if (ns < NNODE) {
        u32 lo = (u32)f2bf(acc[nt][0] + bias[0]) | ((u32)f2bf(acc[nt][1] + bias[1]) << 16);
        u32 hi = (u32)f2bf(acc[nt][2] + bias[2]) | ((u32)f2bf(acc[nt][3] + bias[3]) << 16);
        u32x2 v = {lo, hi};
        *(u32x2*)(T + (size_t)ns * TW + jr) = v;
      }
    }
  }
}

// ---------- kernel 3 (v3): single fat gather phase + 2-pass MFMA/GRU ----------
// Per block: stage all G (100 rows x 768B) in 19 loads/thread, one drain, one barrier.
// B-fragments loaded directly from global A into registers (no A LDS at all).
// Wave w owns h in [32w, 32w+32): staged column permutation gives complete (r,i,n) triples.
__global__ __launch_bounds__(256, 2) void k3_main(
    const int* __restrict__ inputs, const float* __restrict__ A,
    const u16* __restrict__ T, const float* __restrict__ cvec,
    const float* __restrict__ emb, float* __restrict__ out)
{
  __shared__ __align__(128) unsigned char Glds[24 * GSUB];  // 79872 B
  __shared__ u32 rowOff[100];     // byte offset of Gin/Gout row in T
  __shared__ int nodeIdx[64];
  __shared__ float rsLds[2][64];

  const int tid = threadIdx.x;
  const int b = blockIdx.x;
  const int w = tid >> 6, l = tid & 63;
  const int l16 = l & 15, g4 = l >> 4;

  if (tid < 64) nodeIdx[tid] = inputs[b * NS + (tid < NS ? tid : 0)];
  if (tid < 100) {
    int node = inputs[b * NS + (tid < NS ? tid : tid - NS)];
    rowOff[tid] = (u32)node * (TW * 2) + (tid < NS ? 0u : 768u);
  }
  if (tid < 128) ((float*)rsLds)[tid] = 0.f;
  // zero pad rows 100..103 (tile 25) of each gsub
  if (tid < 192) {
    int gs = tid >> 3, q = tid & 7;
    u32x4 z = {0, 0, 0, 0};
    *(u32x4*)(Glds + gs * GSUB + 3200 + q * 16) = z;
  }
  __syncthreads();

  const float* Ab = A + (size_t)b * (NS * 2 * NS);
  const char* Tb = (const char*)T;

  // ---- B-fragments straight from global A (registers, L2-hot) ----
  s16x8 Bf[4][4];
  #pragma unroll
  for (int nt = 0; nt < 4; ++nt) {
    int s = nt * 16 + l16; if (s > NS - 1) s = NS - 1;
    const float* ap = Ab + s * 100;
    #pragma unroll
    for (int kt = 0; kt < 4; ++kt) {
      f32x4 x = {0.f, 0.f, 0.f, 0.f}, y = {0.f, 0.f, 0.f, 0.f};
      if (kt < 3) {
        x = *(const f32x4*)(ap + kt * 32 + g4 * 8);
        y = *(const f32x4*)(ap + kt * 32 + g4 * 8 + 4);
      } else if (g4 == 0) {
        x = *(const f32x4*)(ap + 96);   // t 96..99; 100..103 zero
      }
      Bf[nt][kt] = pack8_trunc(x, y);
    }
  }

  // ---- issue ALL G gather loads (19/thread) ----
  u32x4 st[19];
  #pragma unroll
  for (int i = 0; i < 19; ++i) {
    if (i < 18 || tid < 192) {
      int t, c; stage_decomp(i * 256 + tid, t, c);
      int gbyte = gs_to_gbyte(c >> 1) + (c & 1) * 16;
      st[i] = *(const u32x4*)(Tb + rowOff[t] + gbyte);
    }
  }

  // ---- f32 rowsums (overlapped with gather latency) ----
  if (tid < 100) {
    int s = tid < NS ? tid : tid - NS;
    const float* ap = Ab + s * 100 + (tid < NS ? 0 : NS);
    float sum = 0.f;
    #pragma unroll 10
    for (int t = 0; t < NS; ++t) sum += ap[t];
    rsLds[tid < NS ? 0 : 1][s] = sum;
  }

  // ---- write staged G to LDS (single vmcnt drain) ----
  #pragma unroll
  for (int i = 0; i < 19; ++i) {
    if (i < 18 || tid < 192) {
      int t, c; stage_decomp(i * 256 + tid, t, c);
      *(u32x4*)(Glds + (c >> 1) * GSUB + t * 32 + (c & 1) * 16) = st[i];
    }
  }
  __syncthreads();

  // ---- two passes: pass p covers h in [w*32+p*16, +16) for all 3 gates ----
  const s16x8 zero8 = {0, 0, 0, 0, 0, 0, 0, 0};
  #pragma unroll
  for (int p = 0; p < 2; ++p) {
    f32x4 acc[3][4] = {};
    #pragma unroll
    for (int gate = 0; gate < 3; ++gate) {
      const int gs = w * 6 + gate * 2 + p;
      const unsigned char* gb = Glds + gs * GSUB + l16 * 8;
      s16x8 Af[4];
      afrag_tr8(gb + g4 * 256, gb + 3072, Af);
      if (g4 != 0) Af[3] = zero8;
      #pragma unroll
      for (int kt = 0; kt < 4; ++kt)
        #pragma unroll
        for (int nt = 0; nt < 4; ++nt)
          acc[gate][nt] = __builtin_amdgcn_mfma_f32_16x16x32_bf16(Af[kt], Bf[nt][kt], acc[gate][nt], 0, 0, 0);
    }

    // ---- GRU epilogue for this h-slice ----
    const int h0 = w * 32 + p * 16 + g4 * 4;
    f32x4 cin[3], cou[3], cz[3];
    #pragma unroll
    for (int gate = 0; gate < 3; ++gate) {
      int g = gate * 128 + h0;
      cin[gate] = *(const f32x4*)(cvec + g);
      cou[gate] = *(const f32x4*)(cvec + 384 + g);
      cz[gate]  = *(const f32x4*)(cvec + 768 + g);
    }
    u16x4 gr[4], gi[4], gn[4];
    f32x4 hid[4];
    #pragma unroll
    for (int nt = 0; nt < 4; ++nt) {
      int s = nt * 16 + l16;
      int node = nodeIdx[s];
      const u16* Trow = T + (size_t)node * TW + 768 + h0;
      gr[nt] = *(const u16x4*)(Trow);
      gi[nt] = *(const u16x4*)(Trow + 128);
      gn[nt] = *(const u16x4*)(Trow + 256);
      hid[nt] = *(const f32x4*)(emb + (size_t)node * NH + h0);
    }
    #pragma unroll
    for (int nt = 0; nt < 4; ++nt) {
      int s = nt * 16 + l16;
      float rin = rsLds[0][s], rou = rsLds[1][s];
      f32x4 res;
      #pragma unroll
      for (int r = 0; r < 4; ++r) {
        float vr = acc[0][nt][r] + rin * cin[0][r] + rou * cou[0][r] + cz[0][r] + bf2f(gr[nt][r]);
        float vi = acc[1][nt][r] + rin * cin[1][r] + rou * cou[1][r] + cz[1][r] + bf2f(gi[nt][r]);
        float vn = acc[2][nt][r] + rin * cin[2][r] + rou * cou[2][r] + cz[2][r];
        float rr = sigm(vr);
        float ii = sigm(vi);
        float nn = tanh_(vn + rr * bf2f(gn[nt][r]));
        res[r] = nn + ii * (hid[nt][r] - nn);
      }
      if (s < NS)
        *(f32x4*)(out + ((size_t)b * NS + s) * NH + h0) = res;
    }
  }
}

// ---------- launcher ----------
extern "C" void kernel_launch(void* const* d_in, const int* in_sizes, int n_in,
                              void* d_out, int out_size, void* d_ws, size_t ws_size,
                              hipStream_t stream) {
  const int*   inputs = (const int*)  d_in[0];
  const float* A      = (const float*)d_in[1];
  const float* emb    = (const float*)d_in[2];
  const float* W_in   = (const float*)d_in[3];
  const float* b_in   = (const float*)d_in[4];
  const float* W_out  = (const float*)d_in[5];
  const float* b_out  = (const float*)d_in[6];
  const float* w_ih   = (const float*)d_in[7];
  const float* b_ih   = (const float*)d_in[8];
  const float* w_hh   = (const float*)d_in[9];
  const float* b_hh   = (const float*)d_in[10];
  const float* b_iah  = (const float*)d_in[11];
  const float* b_oah  = (const float*)d_in[12];

  // ws layout: T (50000*1152 bf16 = 115,200,000 B) | UcatT (294,912 B) | cvec (4,608 B)
  u16*   T     = (u16*)d_ws;
  u16*   UcatT = (u16*)((char*)d_ws + 115200000);
  float* cvec  = (float*)((char*)d_ws + 115200000 + 294912);

  k1_prep<<<dim3(581), dim3(256), 0, stream>>>(W_in, b_in, W_out, b_out, w_ih, b_ih,
                                               w_hh, b_iah, b_oah, UcatT, cvec);
  k2_tables<<<dim3(782), dim3(256), 0, stream>>>(emb, UcatT, b_hh, T);
  k3_main<<<dim3(4096), dim3(256), 0, stream>>>(inputs, A, T, cvec, emb, (float*)d_out);
}